// Round 2
// baseline (577.433 us; speedup 1.0000x reference)
//
#include <hip/hip_runtime.h>
#include <hip/hip_bf16.h>
#include <cstdint>
#include <cstddef>

#define NB 32
#define NS 4096
#define NH 512
#define NK 1024   // 2H
#define KC 64     // K-chunk staged in LDS

typedef __attribute__((ext_vector_type(8))) short bf16x8;
typedef __attribute__((ext_vector_type(4))) float f32x4;
typedef __attribute__((ext_vector_type(16))) float f32x16;

__device__ __forceinline__ unsigned short f2bf_s(float f) {
  union { float f; unsigned u; } x; x.f = f;
  unsigned r = x.u + 0x7fffu + ((x.u >> 16) & 1u);   // RNE bf16
  return (unsigned short)(r >> 16);
}

// ---- kernel 1: pack Ua [512 n][1024 k] f32 -> bf16 MFMA-fragment order ----
// out[((kk*16 + ct)*64 + l)*8 + j] = bf16(Ua[ct*32 + (l&31)][kk*16 + (l>>5)*8 + j])
__global__ void k_ua_pack(const float* __restrict__ ua, unsigned short* __restrict__ out) {
  int t = blockIdx.x * 256 + threadIdx.x;   // 65536 threads
  int l = t & 63;
  int ct = (t >> 6) & 15;
  int kk = t >> 10;                          // 0..63
  const float* src = ua + (size_t)(ct * 32 + (l & 31)) * NK + kk * 16 + (l >> 5) * 8;
  float4 a = *(const float4*)src;
  float4 c = *(const float4*)(src + 4);
  ushort4 o0, o1;
  o0.x = f2bf_s(a.x); o0.y = f2bf_s(a.y); o0.z = f2bf_s(a.z); o0.w = f2bf_s(a.w);
  o1.x = f2bf_s(c.x); o1.y = f2bf_s(c.y); o1.z = f2bf_s(c.z); o1.w = f2bf_s(c.w);
  ushort4* dst = (ushort4*)(out + (size_t)t * 8);
  dst[0] = o0; dst[1] = o1;
}

// ---- kernel 2: qproj[b][h] = query[b]·Wa_w[h] + Wa_b[h] + Ua_b[h] ----
__global__ void k_qproj(const float* __restrict__ q, const float* __restrict__ ww,
                        const float* __restrict__ wb, const float* __restrict__ ub,
                        float* __restrict__ qp) {
  int b = blockIdx.y;
  int h = blockIdx.x * 128 + threadIdx.x;
  const float* qr = q + b * NH;
  const float* wr = ww + h * NH;
  float acc = 0.f;
  for (int k = 0; k < NH; k += 4) {
    float4 a = *(const float4*)(qr + k);
    float4 c = *(const float4*)(wr + k);
    acc += a.x * c.x + a.y * c.y + a.z * c.z + a.w * c.w;
  }
  qp[b * NH + h] = acc + wb[h] + ub[h];
}

// ---- kernel 3: scores via 32x32x16 MFMA ----
// block: 512 thr = 8 waves = 2 row-groups(64 rows) x 4 col-groups(128 cols); BM=128.
// A (keys, f32->bf16) staged in LDS (dbuf, XOR-swizzled); B (Ua) from packed global.
__global__ __launch_bounds__(512, 2)
void k_scores2(const float* __restrict__ keys, const unsigned short* __restrict__ uapk,
               const float* __restrict__ qproj, const float* __restrict__ vaw,
               const float* __restrict__ vab, float* __restrict__ scores) {
  __shared__ alignas(16) unsigned short A_lds[2][128 * KC];  // 2 x 16KB
  __shared__ float qp_s[NH];
  __shared__ float va_s[NH];
  __shared__ float red[128][4];

  const int b   = blockIdx.y;
  const int s0  = blockIdx.x * 128;
  const int tid = threadIdx.x;
  const int w   = tid >> 6;
  const int l   = tid & 63;
  const int rg  = w >> 2;     // 0..1
  const int cg  = w & 3;      // 0..3
  const int l31 = l & 31;
  const int lhi = l >> 5;     // 0..1

  qp_s[tid] = qproj[b * NH + tid];
  va_s[tid] = vaw[tid];

  // staging: thread -> row sr = tid&127, k-quarter skq = tid>>7, 16 f32 per chunk
  const int sr  = tid & 127;
  const int skq = tid >> 7;
  const float* kbase = keys + ((size_t)b * NS + s0 + sr) * NK + skq * 16;
  char* const myrow = (char*)&A_lds[0][0];  // indexed manually
  const int wr0 = sr * 128;                       // byte base of row
  const int wo0 = (skq * 32) ^ ((sr & 7) << 4);   // swizzled byte offs in row
  const int wo1 = (skq * 32 + 16) ^ ((sr & 7) << 4);

  f32x16 acc[2][4];
  #pragma unroll
  for (int i = 0; i < 2; ++i)
    #pragma unroll
    for (int j = 0; j < 4; ++j)
      #pragma unroll
      for (int e = 0; e < 16; ++e) acc[i][j][e] = 0.f;

  // A-frag read offsets (bytes): row rr, chunk-local k16 step kk, lane k-half lhi
  const int arow0 = rg * 64 + 0 * 32 + l31;
  const int arow1 = rg * 64 + 1 * 32 + l31;
  const int asw0 = (arow0 & 7) << 4;
  const int asw1 = (arow1 & 7) << 4;

  // prologue: stage chunk 0
  {
    float4 st0 = *(const float4*)(kbase + 0);
    float4 st1 = *(const float4*)(kbase + 4);
    float4 st2 = *(const float4*)(kbase + 8);
    float4 st3 = *(const float4*)(kbase + 12);
    ushort4 p0, p1, p2, p3;
    p0.x=f2bf_s(st0.x); p0.y=f2bf_s(st0.y); p0.z=f2bf_s(st0.z); p0.w=f2bf_s(st0.w);
    p1.x=f2bf_s(st1.x); p1.y=f2bf_s(st1.y); p1.z=f2bf_s(st1.z); p1.w=f2bf_s(st1.w);
    p2.x=f2bf_s(st2.x); p2.y=f2bf_s(st2.y); p2.z=f2bf_s(st2.z); p2.w=f2bf_s(st2.w);
    p3.x=f2bf_s(st3.x); p3.y=f2bf_s(st3.y); p3.z=f2bf_s(st3.z); p3.w=f2bf_s(st3.w);
    *(ushort4*)(myrow + wr0 + wo0)     = p0;
    *(ushort4*)(myrow + wr0 + wo0 + 8) = p1;   // note: +8 shorts = +16B? careful
    // fix: second 16B goes at wo1 (swizzle applied separately)
    *(ushort4*)(myrow + wr0 + wo1)     = p2;
    *(ushort4*)(myrow + wr0 + wo1 + 8) = p3;
  }
  __syncthreads();

  for (int c = 0; c < 16; ++c) {
    const int buf = c & 1;
    const char* Ab = (const char*)&A_lds[buf][0];
    float4 nx0, nx1, nx2, nx3;
    if (c < 15) {
      const float* nb = kbase + (c + 1) * KC;
      nx0 = *(const float4*)(nb + 0);
      nx1 = *(const float4*)(nb + 4);
      nx2 = *(const float4*)(nb + 8);
      nx3 = *(const float4*)(nb + 12);
    }
    #pragma unroll
    for (int kk = 0; kk < 4; ++kk) {
      const int kb = kk * 32 + lhi * 16;
      bf16x8 af0 = *(const bf16x8*)(Ab + arow0 * 128 + (kb ^ asw0));
      bf16x8 af1 = *(const bf16x8*)(Ab + arow1 * 128 + (kb ^ asw1));
      const int kkg = c * 4 + kk;
      const unsigned short* bp = uapk + (((size_t)kkg * 16 + cg * 4) * 64 + l) * 8;
      bf16x8 bf0 = *(const bf16x8*)(bp);
      bf16x8 bf1 = *(const bf16x8*)(bp + 64 * 8);
      bf16x8 bf2 = *(const bf16x8*)(bp + 128 * 8);
      bf16x8 bf3 = *(const bf16x8*)(bp + 192 * 8);
      acc[0][0] = __builtin_amdgcn_mfma_f32_32x32x16_bf16(af0, bf0, acc[0][0], 0, 0, 0);
      acc[1][0] = __builtin_amdgcn_mfma_f32_32x32x16_bf16(af1, bf0, acc[1][0], 0, 0, 0);
      acc[0][1] = __builtin_amdgcn_mfma_f32_32x32x16_bf16(af0, bf1, acc[0][1], 0, 0, 0);
      acc[1][1] = __builtin_amdgcn_mfma_f32_32x32x16_bf16(af1, bf1, acc[1][1], 0, 0, 0);
      acc[0][2] = __builtin_amdgcn_mfma_f32_32x32x16_bf16(af0, bf2, acc[0][2], 0, 0, 0);
      acc[1][2] = __builtin_amdgcn_mfma_f32_32x32x16_bf16(af1, bf2, acc[1][2], 0, 0, 0);
      acc[0][3] = __builtin_amdgcn_mfma_f32_32x32x16_bf16(af0, bf3, acc[0][3], 0, 0, 0);
      acc[1][3] = __builtin_amdgcn_mfma_f32_32x32x16_bf16(af1, bf3, acc[1][3], 0, 0, 0);
    }
    if (c < 15) {
      // write next chunk into buf^1 (its last readers finished before chunk c began)
      char* Aw = (char*)&A_lds[buf ^ 1][0];
      ushort4 p0, p1, p2, p3;
      p0.x=f2bf_s(nx0.x); p0.y=f2bf_s(nx0.y); p0.z=f2bf_s(nx0.z); p0.w=f2bf_s(nx0.w);
      p1.x=f2bf_s(nx1.x); p1.y=f2bf_s(nx1.y); p1.z=f2bf_s(nx1.z); p1.w=f2bf_s(nx1.w);
      p2.x=f2bf_s(nx2.x); p2.y=f2bf_s(nx2.y); p2.z=f2bf_s(nx2.z); p2.w=f2bf_s(nx2.w);
      p3.x=f2bf_s(nx3.x); p3.y=f2bf_s(nx3.y); p3.z=f2bf_s(nx3.z); p3.w=f2bf_s(nx3.w);
      *(ushort4*)(Aw + wr0 + wo0)     = p0;
      *(ushort4*)(Aw + wr0 + wo0 + 8) = p1;
      *(ushort4*)(Aw + wr0 + wo1)     = p2;
      *(ushort4*)(Aw + wr0 + wo1 + 8) = p3;
      __syncthreads();
    }
  }

  // epilogue: score[row] = sum_n va[n]*tanh(qp[n] + kproj[row][n])
  // C layout (m101): col = lane&31, row = (reg&3) + 8*(reg>>2) + 4*(lane>>5)
  #pragma unroll
  for (int rt = 0; rt < 2; ++rt) {
    #pragma unroll
    for (int reg = 0; reg < 16; ++reg) {
      float sum = 0.f;
      #pragma unroll
      for (int ct = 0; ct < 4; ++ct) {
        int n = cg * 128 + ct * 32 + l31;
        float x = qp_s[n] + acc[rt][ct][reg];
        float e = __expf(2.f * x);
        float th = 1.f - 2.f / (e + 1.f);
        sum += va_s[n] * th;
      }
      sum += __shfl_xor(sum, 1);
      sum += __shfl_xor(sum, 2);
      sum += __shfl_xor(sum, 4);
      sum += __shfl_xor(sum, 8);
      sum += __shfl_xor(sum, 16);
      if (l31 == 0) {
        int rloc = (reg & 3) + 8 * (reg >> 2) + 4 * lhi;
        red[rg * 64 + rt * 32 + rloc][cg] = sum;
      }
    }
  }
  __syncthreads();
  if (tid < 128) {
    float s = red[tid][0] + red[tid][1] + red[tid][2] + red[tid][3] + vab[0];
    scores[(size_t)b * NS + s0 + tid] = s;
  }
}

// ---- kernel 4: softmax over scores rows -> attn out ----
__global__ void k_softmax(const float* __restrict__ scores, float* __restrict__ attn) {
  __shared__ float redm[4];
  __shared__ float reds[4];
  int b = blockIdx.x, tid = threadIdx.x;
  const float* row = scores + (size_t)b * NS;
  float v[16];
  float m = -1e30f;
  #pragma unroll
  for (int i = 0; i < 16; ++i) { v[i] = row[i * 256 + tid]; m = fmaxf(m, v[i]); }
  #pragma unroll
  for (int off = 1; off < 64; off <<= 1) m = fmaxf(m, __shfl_xor(m, off));
  if ((tid & 63) == 0) redm[tid >> 6] = m;
  __syncthreads();
  m = fmaxf(fmaxf(redm[0], redm[1]), fmaxf(redm[2], redm[3]));
  float s = 0.f;
  #pragma unroll
  for (int i = 0; i < 16; ++i) { v[i] = expf(v[i] - m); s += v[i]; }
  #pragma unroll
  for (int off = 1; off < 64; off <<= 1) s += __shfl_xor(s, off);
  if ((tid & 63) == 0) reds[tid >> 6] = s;
  __syncthreads();
  s = reds[0] + reds[1] + reds[2] + reds[3];
  float inv = 1.f / s;
  float* o = attn + (size_t)b * NS;
  #pragma unroll
  for (int i = 0; i < 16; ++i) o[i * 256 + tid] = v[i] * inv;
}

// ---- kernel 5: context partials ----
__global__ void k_ctx_partial(const float* __restrict__ keys, const float* __restrict__ attn,
                              float* __restrict__ part) {
  __shared__ float w_s[256];
  int b = blockIdx.y, seg = blockIdx.x, tid = threadIdx.x;
  int sbeg = seg * 256;
  w_s[tid] = attn[(size_t)b * NS + sbeg + tid];
  __syncthreads();
  const float* kp = keys + ((size_t)b * NS + sbeg) * NK + tid * 4;
  float ax = 0.f, ay = 0.f, az = 0.f, aw = 0.f;
  #pragma unroll 4
  for (int s = 0; s < 256; ++s) {
    float4 kv = *(const float4*)(kp + (size_t)s * NK);
    float wv = w_s[s];
    ax += wv * kv.x; ay += wv * kv.y; az += wv * kv.z; aw += wv * kv.w;
  }
  float4 o; o.x = ax; o.y = ay; o.z = az; o.w = aw;
  *(float4*)(part + ((size_t)(seg * NB + b) << 10) + tid * 4) = o;
}

// ---- kernel 6: reduce segment partials -> context ----
__global__ void k_ctx_reduce(const float* __restrict__ part, float* __restrict__ ctx) {
  int i = blockIdx.x * 256 + threadIdx.x;   // 32768
  int b = i >> 10, c = i & 1023;
  float s = 0.f;
  #pragma unroll
  for (int seg = 0; seg < 16; ++seg) s += part[((size_t)(seg * NB + b) << 10) + c];
  ctx[i] = s;
}

extern "C" void kernel_launch(void* const* d_in, const int* in_sizes, int n_in,
                              void* d_out, int out_size, void* d_ws, size_t ws_size,
                              hipStream_t stream) {
  const float* query = (const float*)d_in[0];
  const float* keys  = (const float*)d_in[1];
  const float* Wa_w  = (const float*)d_in[2];
  const float* Wa_b  = (const float*)d_in[3];
  const float* Ua_w  = (const float*)d_in[4];
  const float* Ua_b  = (const float*)d_in[5];
  const float* Va_w  = (const float*)d_in[6];
  const float* Va_b  = (const float*)d_in[7];

  float* out      = (float*)d_out;
  float* ctx_out  = out;             // [32][1024]
  float* attn_out = out + NB * NK;   // [32][4096]

  unsigned short* ua_pk = (unsigned short*)d_ws;                                  // 1 MB
  float* qproj  = (float*)((char*)d_ws + (1u << 20));                             // 64 KB
  float* scores = (float*)((char*)d_ws + (1u << 20) + (1u << 16));                // 512 KB
  float* part   = (float*)((char*)d_ws + (1u << 20) + (1u << 16) + (1u << 19));   // 2 MB

  k_ua_pack<<<256, 256, 0, stream>>>(Ua_w, ua_pk);
  k_qproj<<<dim3(4, NB), 128, 0, stream>>>(query, Wa_w, Wa_b, Ua_b, qproj);
  k_scores2<<<dim3(NS / 128, NB), 512, 0, stream>>>(keys, ua_pk, qproj, Va_w, Va_b, scores);
  k_softmax<<<NB, 256, 0, stream>>>(scores, attn_out);
  k_ctx_partial<<<dim3(16, NB), 256, 0, stream>>>(keys, attn_out, part);
  k_ctx_reduce<<<NB * NK / 256, 256, 0, stream>>>(part, ctx_out);
}

// Round 3
// 420.553 us; speedup vs baseline: 1.3730x; 1.3730x over previous
//
#include <hip/hip_runtime.h>
#include <hip/hip_bf16.h>
#include <cstdint>
#include <cstddef>

#define NB 32
#define NS 4096
#define NH 512
#define NK 1024   // 2H

typedef __attribute__((ext_vector_type(8))) short short8;
typedef __attribute__((ext_vector_type(4))) float f32x4;

__device__ __forceinline__ unsigned short f2bf_s(float f) {
  union { float f; unsigned u; } x; x.f = f;
  unsigned r = x.u + 0x7fffu + ((x.u >> 16) & 1u);   // RNE bf16
  return (unsigned short)(r >> 16);
}

__device__ __forceinline__ void gload16(const void* g, void* l) {
  __builtin_amdgcn_global_load_lds(
      (const __attribute__((address_space(1))) unsigned int*)g,
      (__attribute__((address_space(3))) unsigned int*)l, 16, 0, 0);
}

// ---- kernel 1: pack Ua [512 n][1024 k] f32 -> bf16, pre-swizzled LDS-linear order ----
// layout: [bn(2)][kc(16)][chunk c(2048) of 16B]; c: nloc=c>>3, k16=(c&7)^(nloc&7)
// content: bf16 Ua[bn*256+nloc][kc*64 + k16*8 + j], j=0..7
__global__ void k_ua_pack(const float* __restrict__ ua, unsigned short* __restrict__ out) {
  int t = blockIdx.x * 256 + threadIdx.x;   // 65536 chunks
  int c = t & 2047;
  int kc = (t >> 11) & 15;
  int bn = t >> 15;
  int nloc = c >> 3;
  int k16 = (c & 7) ^ (nloc & 7);
  const float* src = ua + (size_t)(bn * 256 + nloc) * NK + kc * 64 + k16 * 8;
  float4 a = *(const float4*)src;
  float4 b2 = *(const float4*)(src + 4);
  ushort4 o0, o1;
  o0.x = f2bf_s(a.x);  o0.y = f2bf_s(a.y);  o0.z = f2bf_s(a.z);  o0.w = f2bf_s(a.w);
  o1.x = f2bf_s(b2.x); o1.y = f2bf_s(b2.y); o1.z = f2bf_s(b2.z); o1.w = f2bf_s(b2.w);
  ushort4* dst = (ushort4*)(out + (size_t)t * 8);
  dst[0] = o0; dst[1] = o1;
}

// ---- kernel 2: qproj[b][h] = query[b]·Wa_w[h] + Wa_b[h] + Ua_b[h] ----
__global__ void k_qproj(const float* __restrict__ q, const float* __restrict__ ww,
                        const float* __restrict__ wb, const float* __restrict__ ub,
                        float* __restrict__ qp) {
  int b = blockIdx.y;
  int h = blockIdx.x * 128 + threadIdx.x;
  const float* qr = q + b * NH;
  const float* wr = ww + h * NH;
  float acc = 0.f;
  for (int k = 0; k < NH; k += 4) {
    float4 a = *(const float4*)(qr + k);
    float4 c = *(const float4*)(wr + k);
    acc += a.x * c.x + a.y * c.y + a.z * c.z + a.w * c.w;
  }
  qp[b * NH + h] = acc + wb[h] + ub[h];
}

// ---- kernel 3: scores partials, 256x256 tile, 16x16x32 MFMA, dbuf LDS ----
// grid (16 sblk, 2 bn, 32 b), 512 thr = 8 waves = 2 rg x 4 cg, wave tile 128x64.
__global__ __launch_bounds__(512, 2)
void k_scores3(const float* __restrict__ keys, const unsigned short* __restrict__ uapk,
               const float* __restrict__ qproj, const float* __restrict__ vaw,
               float* __restrict__ scores_part) {
  __shared__ alignas(16) unsigned short Albuf[2][256 * 64];  // 2 x 32KB
  __shared__ alignas(16) unsigned short Blbuf[2][256 * 64];  // 2 x 32KB
  __shared__ float qp_s[NH];
  __shared__ float va_s[NH];
  __shared__ float red[256][4];

  const int sblk = blockIdx.x;
  const int bn   = blockIdx.y;
  const int b    = blockIdx.z;
  const int tid  = threadIdx.x;
  const int w    = tid >> 6;
  const int l    = tid & 63;
  const int rg   = w >> 2;      // 0..1
  const int cg   = w & 3;       // 0..3
  const int l15  = l & 15;
  const int lq   = l >> 4;      // 0..3
  const int asw  = (l15 & 7) << 4;   // read-side swizzle (row&7 == l15&7)

  qp_s[tid] = qproj[b * NH + tid];
  va_s[tid] = vaw[tid];

  // A staging map: thread -> row srow=tid>>1 (0..255), k-half skh=tid&1 (32 floats)
  const int srow = tid >> 1;
  const int skh  = tid & 1;
  const float* agbase = keys + ((size_t)b * NS + sblk * 256 + srow) * NK + skh * 32;
  const int wsw = (srow & 7) << 4;
  const int wbase = srow * 128;      // byte base of LDS row

  // B staging: per wave 4 x gload16; global src linear == LDS linear (pre-swizzled pack)
  const char* bgbase = (const char*)uapk + (size_t)bn * 16 * 32768 + w * 4096 + l * 16;

  f32x4 acc[8][4];
  #pragma unroll
  for (int i = 0; i < 8; ++i)
    #pragma unroll
    for (int j = 0; j < 4; ++j)
      acc[i][j] = (f32x4){0.f, 0.f, 0.f, 0.f};

  // ---- prologue: stage chunk 0 into buf 0 ----
  {
    float4 ar0 = *(const float4*)(agbase + 0);
    float4 ar1 = *(const float4*)(agbase + 4);
    float4 ar2 = *(const float4*)(agbase + 8);
    float4 ar3 = *(const float4*)(agbase + 12);
    float4 ar4 = *(const float4*)(agbase + 16);
    float4 ar5 = *(const float4*)(agbase + 20);
    float4 ar6 = *(const float4*)(agbase + 24);
    float4 ar7 = *(const float4*)(agbase + 28);
    #pragma unroll
    for (int j2 = 0; j2 < 4; ++j2)
      gload16(bgbase + j2 * 1024, (char*)&Blbuf[0][0] + w * 4096 + j2 * 1024);
    char* Aw = (char*)&Albuf[0][0];
    short8 p0, p1, p2, p3;
    p0[0]=f2bf_s(ar0.x); p0[1]=f2bf_s(ar0.y); p0[2]=f2bf_s(ar0.z); p0[3]=f2bf_s(ar0.w);
    p0[4]=f2bf_s(ar1.x); p0[5]=f2bf_s(ar1.y); p0[6]=f2bf_s(ar1.z); p0[7]=f2bf_s(ar1.w);
    p1[0]=f2bf_s(ar2.x); p1[1]=f2bf_s(ar2.y); p1[2]=f2bf_s(ar2.z); p1[3]=f2bf_s(ar2.w);
    p1[4]=f2bf_s(ar3.x); p1[5]=f2bf_s(ar3.y); p1[6]=f2bf_s(ar3.z); p1[7]=f2bf_s(ar3.w);
    p2[0]=f2bf_s(ar4.x); p2[1]=f2bf_s(ar4.y); p2[2]=f2bf_s(ar4.z); p2[3]=f2bf_s(ar4.w);
    p2[4]=f2bf_s(ar5.x); p2[5]=f2bf_s(ar5.y); p2[6]=f2bf_s(ar5.z); p2[7]=f2bf_s(ar5.w);
    p3[0]=f2bf_s(ar6.x); p3[1]=f2bf_s(ar6.y); p3[2]=f2bf_s(ar6.z); p3[3]=f2bf_s(ar6.w);
    p3[4]=f2bf_s(ar7.x); p3[5]=f2bf_s(ar7.y); p3[6]=f2bf_s(ar7.z); p3[7]=f2bf_s(ar7.w);
    *(short8*)(Aw + wbase + ((skh * 64 +  0) ^ wsw)) = p0;
    *(short8*)(Aw + wbase + ((skh * 64 + 16) ^ wsw)) = p1;
    *(short8*)(Aw + wbase + ((skh * 64 + 32) ^ wsw)) = p2;
    *(short8*)(Aw + wbase + ((skh * 64 + 48) ^ wsw)) = p3;
  }
  __syncthreads();

  // ---- main loop over K chunks ----
  for (int kc = 0; kc < 16; ++kc) {
    const int cur = kc & 1;
    const char* Ab = (const char*)&Albuf[cur][0];
    const char* Bb = (const char*)&Blbuf[cur][0];

    float4 ar0, ar1, ar2, ar3, ar4, ar5, ar6, ar7;
    if (kc < 15) {
      const float* ag = agbase + (kc + 1) * 64;
      ar0 = *(const float4*)(ag + 0);
      ar1 = *(const float4*)(ag + 4);
      ar2 = *(const float4*)(ag + 8);
      ar3 = *(const float4*)(ag + 12);
      ar4 = *(const float4*)(ag + 16);
      ar5 = *(const float4*)(ag + 20);
      ar6 = *(const float4*)(ag + 24);
      ar7 = *(const float4*)(ag + 28);
      const char* bg = bgbase + (size_t)(kc + 1) * 32768;
      #pragma unroll
      for (int j2 = 0; j2 < 4; ++j2)
        gload16(bg + j2 * 1024, (char*)&Blbuf[cur ^ 1][0] + w * 4096 + j2 * 1024);
    }

    #pragma unroll
    for (int h = 0; h < 2; ++h) {
      short8 bf[4];
      #pragma unroll
      for (int ct = 0; ct < 4; ++ct) {
        int nrow = cg * 64 + ct * 16 + l15;
        bf[ct] = *(const short8*)(Bb + nrow * 128 + ((h * 64 + lq * 16) ^ asw));
      }
      #pragma unroll
      for (int rh = 0; rh < 2; ++rh) {
        short8 af[4];
        #pragma unroll
        for (int r4 = 0; r4 < 4; ++r4) {
          int arow = rg * 128 + (rh * 4 + r4) * 16 + l15;
          af[r4] = *(const short8*)(Ab + arow * 128 + ((h * 64 + lq * 16) ^ asw));
        }
        __builtin_amdgcn_s_setprio(1);
        #pragma unroll
        for (int r4 = 0; r4 < 4; ++r4)
          #pragma unroll
          for (int ct = 0; ct < 4; ++ct)
            acc[rh * 4 + r4][ct] =
                __builtin_amdgcn_mfma_f32_16x16x32_bf16(af[r4], bf[ct], acc[rh * 4 + r4][ct], 0, 0, 0);
        __builtin_amdgcn_s_setprio(0);
      }
    }

    if (kc < 15) {
      char* Aw = (char*)&Albuf[cur ^ 1][0];
      short8 p0, p1, p2, p3;
      p0[0]=f2bf_s(ar0.x); p0[1]=f2bf_s(ar0.y); p0[2]=f2bf_s(ar0.z); p0[3]=f2bf_s(ar0.w);
      p0[4]=f2bf_s(ar1.x); p0[5]=f2bf_s(ar1.y); p0[6]=f2bf_s(ar1.z); p0[7]=f2bf_s(ar1.w);
      p1[0]=f2bf_s(ar2.x); p1[1]=f2bf_s(ar2.y); p1[2]=f2bf_s(ar2.z); p1[3]=f2bf_s(ar2.w);
      p1[4]=f2bf_s(ar3.x); p1[5]=f2bf_s(ar3.y); p1[6]=f2bf_s(ar3.z); p1[7]=f2bf_s(ar3.w);
      p2[0]=f2bf_s(ar4.x); p2[1]=f2bf_s(ar4.y); p2[2]=f2bf_s(ar4.z); p2[3]=f2bf_s(ar4.w);
      p2[4]=f2bf_s(ar5.x); p2[5]=f2bf_s(ar5.y); p2[6]=f2bf_s(ar5.z); p2[7]=f2bf_s(ar5.w);
      p3[0]=f2bf_s(ar6.x); p3[1]=f2bf_s(ar6.y); p3[2]=f2bf_s(ar6.z); p3[3]=f2bf_s(ar6.w);
      p3[4]=f2bf_s(ar7.x); p3[5]=f2bf_s(ar7.y); p3[6]=f2bf_s(ar7.z); p3[7]=f2bf_s(ar7.w);
      *(short8*)(Aw + wbase + ((skh * 64 +  0) ^ wsw)) = p0;
      *(short8*)(Aw + wbase + ((skh * 64 + 16) ^ wsw)) = p1;
      *(short8*)(Aw + wbase + ((skh * 64 + 32) ^ wsw)) = p2;
      *(short8*)(Aw + wbase + ((skh * 64 + 48) ^ wsw)) = p3;
    }
    __syncthreads();
  }

  // ---- epilogue: partial score over this block's 256 n-cols ----
  #pragma unroll
  for (int rt = 0; rt < 8; ++rt) {
    #pragma unroll
    for (int reg = 0; reg < 4; ++reg) {
      float sum = 0.f;
      #pragma unroll
      for (int ct = 0; ct < 4; ++ct) {
        int gn = bn * 256 + cg * 64 + ct * 16 + l15;
        float x = qp_s[gn] + acc[rt][ct][reg];
        float e = __expf(2.f * x);
        float th = 1.f - __fdividef(2.f, e + 1.f);
        sum += va_s[gn] * th;
      }
      sum += __shfl_xor(sum, 1);
      sum += __shfl_xor(sum, 2);
      sum += __shfl_xor(sum, 4);
      sum += __shfl_xor(sum, 8);
      if (l15 == 0)
        red[rg * 128 + rt * 16 + lq * 4 + reg][cg] = sum;
    }
  }
  __syncthreads();
  if (tid < 256) {
    float s = red[tid][0] + red[tid][1] + red[tid][2] + red[tid][3];
    scores_part[((size_t)bn * NB + b) * NS + sblk * 256 + tid] = s;
  }
}

// ---- kernel 4: softmax over (part0 + part1 + vab) -> attn out ----
__global__ void k_softmax(const float* __restrict__ sp, const float* __restrict__ vab,
                          float* __restrict__ attn) {
  __shared__ float redm[4];
  __shared__ float reds[4];
  int b = blockIdx.x, tid = threadIdx.x;
  const float* r0 = sp + (size_t)b * NS;
  const float* r1 = sp + (size_t)(NB + b) * NS;
  float vb = vab[0];
  float v[16];
  float m = -1e30f;
  #pragma unroll
  for (int i = 0; i < 16; ++i) {
    int idx = i * 256 + tid;
    v[i] = r0[idx] + r1[idx] + vb;
    m = fmaxf(m, v[i]);
  }
  #pragma unroll
  for (int off = 1; off < 64; off <<= 1) m = fmaxf(m, __shfl_xor(m, off));
  if ((tid & 63) == 0) redm[tid >> 6] = m;
  __syncthreads();
  m = fmaxf(fmaxf(redm[0], redm[1]), fmaxf(redm[2], redm[3]));
  float s = 0.f;
  #pragma unroll
  for (int i = 0; i < 16; ++i) { v[i] = expf(v[i] - m); s += v[i]; }
  #pragma unroll
  for (int off = 1; off < 64; off <<= 1) s += __shfl_xor(s, off);
  if ((tid & 63) == 0) reds[tid >> 6] = s;
  __syncthreads();
  s = reds[0] + reds[1] + reds[2] + reds[3];
  float inv = 1.f / s;
  float* o = attn + (size_t)b * NS;
  #pragma unroll
  for (int i = 0; i < 16; ++i) o[i * 256 + tid] = v[i] * inv;
}

// ---- kernel 5: context partials (8 segments of 512 s-rows) ----
__global__ void k_ctx_partial(const float* __restrict__ keys, const float* __restrict__ attn,
                              float* __restrict__ part) {
  __shared__ float w_s[512];
  int b = blockIdx.y, seg = blockIdx.x, tid = threadIdx.x;
  int sbeg = seg * 512;
  w_s[tid] = attn[(size_t)b * NS + sbeg + tid];
  w_s[tid + 256] = attn[(size_t)b * NS + sbeg + 256 + tid];
  __syncthreads();
  const float* kp = keys + ((size_t)b * NS + sbeg) * NK + tid * 4;
  float ax = 0.f, ay = 0.f, az = 0.f, aw = 0.f;
  #pragma unroll 4
  for (int s = 0; s < 512; ++s) {
    float4 kv = *(const float4*)(kp + (size_t)s * NK);
    float wv = w_s[s];
    ax += wv * kv.x; ay += wv * kv.y; az += wv * kv.z; aw += wv * kv.w;
  }
  float4 o; o.x = ax; o.y = ay; o.z = az; o.w = aw;
  *(float4*)(part + ((size_t)(seg * NB + b) << 10) + tid * 4) = o;
}

// ---- kernel 6: reduce 8 segment partials -> context ----
__global__ void k_ctx_reduce(const float* __restrict__ part, float* __restrict__ ctx) {
  int i = blockIdx.x * 256 + threadIdx.x;   // 32768
  int b = i >> 10, c = i & 1023;
  float s = 0.f;
  #pragma unroll
  for (int seg = 0; seg < 8; ++seg) s += part[((size_t)(seg * NB + b) << 10) + c];
  ctx[i] = s;
}

extern "C" void kernel_launch(void* const* d_in, const int* in_sizes, int n_in,
                              void* d_out, int out_size, void* d_ws, size_t ws_size,
                              hipStream_t stream) {
  const float* query = (const float*)d_in[0];
  const float* keys  = (const float*)d_in[1];
  const float* Wa_w  = (const float*)d_in[2];
  const float* Wa_b  = (const float*)d_in[3];
  const float* Ua_w  = (const float*)d_in[4];
  const float* Ua_b  = (const float*)d_in[5];
  const float* Va_w  = (const float*)d_in[6];
  const float* Va_b  = (const float*)d_in[7];

  float* out      = (float*)d_out;
  float* ctx_out  = out;             // [32][1024]
  float* attn_out = out + NB * NK;   // [32][4096]

  unsigned short* ua_pk = (unsigned short*)d_ws;                       // 1 MB
  float* qproj  = (float*)((char*)d_ws + (1u << 20));                  // 64 KB
  float* spart  = (float*)((char*)d_ws + (1u << 20) + (1u << 16));     // 1 MB
  float* part   = (float*)((char*)d_ws + (2u << 20) + (1u << 16));     // 1 MB

  k_ua_pack<<<256, 256, 0, stream>>>(Ua_w, ua_pk);
  k_qproj<<<dim3(4, NB), 128, 0, stream>>>(query, Wa_w, Wa_b, Ua_b, qproj);
  k_scores3<<<dim3(16, 2, NB), 512, 0, stream>>>(keys, ua_pk, qproj, Va_w, spart);
  k_softmax<<<NB, 256, 0, stream>>>(spart, Va_b, attn_out);
  k_ctx_partial<<<dim3(8, NB), 256, 0, stream>>>(keys, attn_out, part);
  k_ctx_reduce<<<NB * NK / 256, 256, 0, stream>>>(part, ctx_out);
}